// Round 12
// baseline (61.150 us; speedup 1.0000x reference)
//
#include <hip/hip_runtime.h>
#include <math.h>

#define B_ 4
#define N_ 8192
#define M_ 8192
#define THREADS 256     // 4 waves per block
#define QB 128          // query rows per block (4 waves x 32)
#define MSPLIT 8        // target-dim split across blocks
#define MCH (M_ / MSPLIT)   // 1024 cols per block
#define TC 512          // targets per LDS chunk
#define NQTOT (B_ * (N_ + M_))   // 65536 min-slots
#define RBLK 256
#define PB_OFF (NQTOT * 4 + RBLK * 4)          // byte offset of packed-B in ws
#define WS_NEED (PB_OFF + (size_t)B_ * M_ * 32)

typedef __attribute__((ext_vector_type(8)))  short bf16x8;   // 8 bf16 = 4 VGPR
typedef __attribute__((ext_vector_type(16))) float f32x16;   // MFMA 32x32 acc

__device__ __forceinline__ unsigned short rne_bf16(float f) {
    unsigned u = __float_as_uint(f);
    return (unsigned short)((u + 0x7FFFu + ((u >> 16) & 1u)) >> 16);
}
__device__ __forceinline__ float bf16_up(unsigned short h) {
    return __uint_as_float(((unsigned)h) << 16);
}
__device__ __forceinline__ void split2(float v, short& hi, short& lo) {
    unsigned short h = rne_bf16(v);
    hi = (short)h;
    lo = (short)rne_bf16(v - bf16_up(h));
}
__device__ __forceinline__ float min3f(float a, float b, float c) {
    return fminf(fminf(a, b), c);   // -> v_min3_f32
}

// ---------- init: +inf bits ----------
__global__ void cd_init_kernel(unsigned* __restrict__ p, int n) {
    int i = blockIdx.x * blockDim.x + threadIdx.x;
    if (i < n) p[i] = 0x7F800000u;
}

// ---------- pack targets into MFMA B-fragments once (kills 64x redundancy) ----------
__global__ __launch_bounds__(256) void cd_pack(
        const float* __restrict__ xyz2, short* __restrict__ pB) {
    const int g = blockIdx.x * 256 + threadIdx.x;   // 0 .. B*M-1
    const float gx = xyz2[g * 3 + 0], gy = xyz2[g * 3 + 1], gz = xyz2[g * 3 + 2];
    short hgx, lgx, hgy, lgy, hgz, lgz, hS, lS;
    split2(gx, hgx, lgx);
    split2(gy, hgy, lgy);
    split2(gz, hgz, lgz);
    const float S = fmaf(gx, gx, fmaf(gy, gy, gz * gz));
    split2(S, hS, lS);
    const short ONE = (short)0x3F80;
    bf16x8 h0 = (bf16x8){hgx, lgx, hgx, hgy, lgy, hgy, hgz, lgz}; // k0-7
    bf16x8 h1 = (bf16x8){hgz, hS, lS, ONE, ONE, 0, 0, 0};         // k8-15
    // layout: [tile_global][kh][col] 16B frags; tile_global = g>>5, col = g&31
    short* dst = pB + ((size_t)(g >> 5) * 64 + (g & 31)) * 8;
    *(bf16x8*)dst = h0;
    *(bf16x8*)(dst + 32 * 8) = h1;
}

// ---------- MFMA chamfer: col-split, ILP-4, precomputed B ----------
__global__ __launch_bounds__(THREADS) void cd_mfma(
        const float* __restrict__ xyz1, const short* __restrict__ pB,
        unsigned* __restrict__ gmin1, unsigned* __restrict__ gmin2) {
    __shared__ short    sB[TC * 16];     // 1024 packed frags, 16KB
    __shared__ unsigned sCol[MCH];       // running col-min (d^2 bits), 4KB

    const int b     = blockIdx.y;
    const int mbase = blockIdx.z * MCH;
    const int tid   = threadIdx.x;
    const int lane  = tid & 63;
    const int wave  = tid >> 6;
    const float* P1 = xyz1 + (size_t)b * N_ * 3;

    for (int i = tid; i < MCH; i += THREADS) sCol[i] = 0x7F800000u;

    // ---- A fragment: row = lane&31 (query), k-half = lane>>5, built once ----
    const int qrow = blockIdx.x * QB + wave * 32 + (lane & 31);
    const float qx = P1[qrow * 3 + 0], qy = P1[qrow * 3 + 1], qz = P1[qrow * 3 + 2];
    short hax, lax, hay, lay, haz, laz, hP, lP;
    split2(-2.0f * qx, hax, lax);
    split2(-2.0f * qy, hay, lay);
    split2(-2.0f * qz, haz, laz);
    const float Pq = fmaf(qx, qx, fmaf(qy, qy, qz * qz));
    split2(Pq, hP, lP);
    const short ONE = (short)0x3F80;
    bf16x8 afrag;
    if (lane < 32) afrag = (bf16x8){hax, hax, lax, hay, hay, lay, haz, haz}; // k0-7
    else           afrag = (bf16x8){laz, ONE, ONE, hP, lP, 0, 0, 0};         // k8-15

    float rmin[16];
#pragma unroll
    for (int r = 0; r < 16; ++r) rmin[r] = INFINITY;

    const f32x16 zacc = {};

    auto POST = [&](const f32x16& ac, int col) {
#pragma unroll
        for (int r = 0; r < 16; ++r) rmin[r] = fminf(rmin[r], ac[r]);
        float t0 = min3f(ac[0],  ac[1],  ac[2]);
        float t1 = min3f(ac[3],  ac[4],  ac[5]);
        float t2 = min3f(ac[6],  ac[7],  ac[8]);
        float t3 = min3f(ac[9],  ac[10], ac[11]);
        float t4 = min3f(ac[12], ac[13], ac[14]);
        float u0 = min3f(t0, t1, t2);
        float u1 = min3f(t3, t4, ac[15]);
        float m  = fmaxf(fminf(u0, u1), 0.0f);
        m = fminf(m, __shfl_xor(m, 32));          // merge the two k-half row groups
        if (lane < 32) atomicMin(&sCol[col], __float_as_uint(m));
    };

    for (int c0 = 0; c0 < MCH; c0 += TC) {
        __syncthreads();                 // protect sB from previous readers
        // ---- stage: pure 16KB copy of precomputed fragments ----
        {
            const bf16x8* src = (const bf16x8*)(pB + (size_t)(b * (M_ / 32) + ((mbase + c0) >> 5)) * 512);
            bf16x8* dst = (bf16x8*)sB;
            for (int p = tid; p < TC * 2; p += THREADS) dst[p] = src[p];
        }
        __syncthreads();

        // ---- 16 tiles of 32 cols; ILP-4 ----
        for (int tl = 0; tl < TC / 32; tl += 4) {
            bf16x8 b0 = ((bf16x8*)sB)[(tl + 0) * 64 + lane];
            bf16x8 b1 = ((bf16x8*)sB)[(tl + 1) * 64 + lane];
            bf16x8 b2 = ((bf16x8*)sB)[(tl + 2) * 64 + lane];
            bf16x8 b3 = ((bf16x8*)sB)[(tl + 3) * 64 + lane];
            f32x16 a0 = __builtin_amdgcn_mfma_f32_32x32x16_bf16(afrag, b0, zacc, 0, 0, 0);
            f32x16 a1 = __builtin_amdgcn_mfma_f32_32x32x16_bf16(afrag, b1, zacc, 0, 0, 0);
            f32x16 a2 = __builtin_amdgcn_mfma_f32_32x32x16_bf16(afrag, b2, zacc, 0, 0, 0);
            f32x16 a3 = __builtin_amdgcn_mfma_f32_32x32x16_bf16(afrag, b3, zacc, 0, 0, 0);
            const int cb = c0 + tl * 32 + (lane & 31);
            POST(a0, cb);
            POST(a1, cb + 32);
            POST(a2, cb + 64);
            POST(a3, cb + 96);
        }
    }

    // ---- query-min: reduce across the 32 col-lanes; atomicMin (col-split) ----
#pragma unroll
    for (int s = 1; s <= 16; s <<= 1) {
#pragma unroll
        for (int r = 0; r < 16; ++r) rmin[r] = fminf(rmin[r], __shfl_xor(rmin[r], s));
    }
    if ((lane & 31) == 0) {
        const int h = lane >> 5;
#pragma unroll
        for (int r = 0; r < 16; ++r) {
            const int row = (r & 3) + 8 * (r >> 2) + 4 * h;   // verified C/D mapping
            atomicMin(&gmin1[(size_t)b * N_ + blockIdx.x * QB + wave * 32 + row],
                      __float_as_uint(fmaxf(rmin[r], 0.0f)));
        }
    }

    // ---- target-min: merge block-local col-mins to global ----
    __syncthreads();
    for (int i = tid; i < MCH; i += THREADS)
        atomicMin(&gmin2[(size_t)b * M_ + mbase + i], sCol[i]);
}

// ---------- reduce A: 256 blocks x 256 -> partials (sqrt of d^2 here) ----------
__global__ __launch_bounds__(RBLK) void cd_reduceA(
        const unsigned* __restrict__ mins, float* __restrict__ partials) {
    __shared__ float sdata[RBLK];
    const int tid = threadIdx.x;
    const int i = blockIdx.x * RBLK + tid;
    float v = sqrtf(__uint_as_float(mins[i]));
    float scale = (i < B_ * N_) ? (1.0f / (float)(B_ * N_)) : (1.0f / (float)(B_ * M_));
    sdata[tid] = v * scale;
    __syncthreads();
    for (int off = RBLK / 2; off > 0; off >>= 1) {
        if (tid < off) sdata[tid] += sdata[tid + off];
        __syncthreads();
    }
    if (tid == 0) partials[blockIdx.x] = sdata[0];
}

__global__ __launch_bounds__(RBLK) void cd_reduceB(
        const float* __restrict__ partials, float* __restrict__ out) {
    __shared__ float sdata[RBLK];
    const int tid = threadIdx.x;
    sdata[tid] = partials[tid];
    __syncthreads();
    for (int off = RBLK / 2; off > 0; off >>= 1) {
        if (tid < off) sdata[tid] += sdata[tid + off];
        __syncthreads();
    }
    if (tid == 0) out[0] = sdata[0];
}

// ---------- fallback (tiny ws): scalar full-loop + atomicAdd ----------
#define FQPT 8
#define FTCH 256
__global__ void cd_zero_out(float* out) { if (threadIdx.x == 0) out[0] = 0.0f; }

__global__ __launch_bounds__(THREADS) void cd_full_kernel(
        const float* __restrict__ Q, const float* __restrict__ T,
        float* __restrict__ out, int nq, int nt, float scale) {
    __shared__ float4 tile[FTCH];
    __shared__ float sdata[THREADS];
    const int b = blockIdx.y;
    const float* Qb = Q + (size_t)b * nq * 3;
    const float* Tbase = T + (size_t)b * nt * 3;
    float m2x[FQPT], m2y[FQPT], m2z[FQPT], c[FQPT], dmin[FQPT];
    const int qbase = blockIdx.x * (THREADS * FQPT) + threadIdx.x;
#pragma unroll
    for (int k = 0; k < FQPT; ++k) {
        int q = qbase + k * THREADS;
        float x = Qb[q * 3 + 0], y = Qb[q * 3 + 1], z = Qb[q * 3 + 2];
        m2x[k] = -2.0f * x; m2y[k] = -2.0f * y; m2z[k] = -2.0f * z;
        c[k] = x * x + y * y + z * z;
        dmin[k] = INFINITY;
    }
    for (int t0 = 0; t0 < nt; t0 += FTCH) {
        __syncthreads();
        for (int j = threadIdx.x; j < FTCH; j += THREADS) {
            const float* Tb = Tbase + (size_t)(t0 + j) * 3;
            float x = Tb[0], y = Tb[1], z = Tb[2];
            tile[j] = make_float4(x, y, z, x * x + y * y + z * z);
        }
        __syncthreads();
#pragma unroll 4
        for (int j = 0; j < FTCH; ++j) {
            float4 t = tile[j];
#pragma unroll
            for (int k = 0; k < FQPT; ++k) {
                float d = fmaf(m2x[k], t.x, t.w);
                d = fmaf(m2y[k], t.y, d);
                d = fmaf(m2z[k], t.z, d);
                dmin[k] = fminf(dmin[k], d);
            }
        }
    }
    float s = 0.0f;
#pragma unroll
    for (int k = 0; k < FQPT; ++k) s += sqrtf(fmaxf(c[k] + dmin[k], 0.0f));
    sdata[threadIdx.x] = s;
    __syncthreads();
    for (int off = THREADS / 2; off > 0; off >>= 1) {
        if (threadIdx.x < off) sdata[threadIdx.x] += sdata[threadIdx.x + off];
        __syncthreads();
    }
    if (threadIdx.x == 0) atomicAdd(out, sdata[0] * scale);
}

extern "C" void kernel_launch(void* const* d_in, const int* in_sizes, int n_in,
                              void* d_out, int out_size, void* d_ws, size_t ws_size,
                              hipStream_t stream) {
    const float* xyz1 = (const float*)d_in[0];
    const float* xyz2 = (const float*)d_in[1];
    float* out = (float*)d_out;

    if (ws_size >= WS_NEED) {
        unsigned* mins = (unsigned*)d_ws;
        float* partials = (float*)((char*)d_ws + (size_t)NQTOT * 4);
        short* pB = (short*)((char*)d_ws + PB_OFF);

        cd_init_kernel<<<NQTOT / 256, 256, 0, stream>>>(mins, NQTOT);
        cd_pack<<<B_ * M_ / 256, 256, 0, stream>>>(xyz2, pB);

        dim3 g(N_ / QB, B_, MSPLIT);   // (64, 4, 8) = 2048 blocks
        cd_mfma<<<g, THREADS, 0, stream>>>(xyz1, pB, mins, mins + (size_t)B_ * N_);

        cd_reduceA<<<NQTOT / RBLK, RBLK, 0, stream>>>(mins, partials);
        cd_reduceB<<<1, RBLK, 0, stream>>>(partials, out);
    } else {
        cd_zero_out<<<1, 64, 0, stream>>>(out);
        dim3 g1(N_ / (THREADS * FQPT), B_);
        cd_full_kernel<<<g1, THREADS, 0, stream>>>(xyz1, xyz2, out, N_, M_,
                                                   1.0f / (float)(B_ * N_));
        dim3 g2(M_ / (THREADS * FQPT), B_);
        cd_full_kernel<<<g2, THREADS, 0, stream>>>(xyz2, xyz1, out, M_, N_,
                                                   1.0f / (float)(B_ * M_));
    }
}

// Round 13
// 46.834 us; speedup vs baseline: 1.3057x; 1.3057x over previous
//
#include <hip/hip_runtime.h>
#include <math.h>

#define B_ 4
#define N_ 8192
#define M_ 8192
#define THREADS 256     // 4 waves per block
#define QB 128          // query rows per block (4 waves x 32)
#define TC 512          // targets per LDS chunk (16 tiles)
#define NQTOT (B_ * (N_ + M_))
#define RBLK 256
#define PB_BYTES ((size_t)B_ * M_ * 32)          // one packed cloud
#define PB1_OFF ((size_t)NQTOT * 4 + RBLK * 4)
#define PB2_OFF (PB1_OFF + PB_BYTES)
#define WS_NEED (PB2_OFF + PB_BYTES)

typedef __attribute__((ext_vector_type(8)))  short bf16x8;   // 8 bf16 = 4 VGPR
typedef __attribute__((ext_vector_type(16))) float f32x16;   // MFMA 32x32 acc

__device__ __forceinline__ unsigned short rne_bf16(float f) {
    unsigned u = __float_as_uint(f);
    return (unsigned short)((u + 0x7FFFu + ((u >> 16) & 1u)) >> 16);
}
__device__ __forceinline__ float bf16_up(unsigned short h) {
    return __uint_as_float(((unsigned)h) << 16);
}
__device__ __forceinline__ void split2(float v, short& hi, short& lo) {
    unsigned short h = rne_bf16(v);
    hi = (short)h;
    lo = (short)rne_bf16(v - bf16_up(h));
}

// ---------- pack both clouds into MFMA B-fragments (once per call) ----------
__global__ __launch_bounds__(256) void cd_pack(
        const float* __restrict__ xyz1, const float* __restrict__ xyz2,
        short* __restrict__ pB1, short* __restrict__ pB2) {
    const int g = blockIdx.x * 256 + threadIdx.x;   // 0 .. B*M-1
    const short ONE = (short)0x3F80;
#pragma unroll
    for (int s = 0; s < 2; ++s) {
        const float* src = s ? xyz2 : xyz1;
        short* dst = s ? pB2 : pB1;
        const float gx = src[g * 3 + 0], gy = src[g * 3 + 1], gz = src[g * 3 + 2];
        short hgx, lgx, hgy, lgy, hgz, lgz, hS, lS;
        split2(gx, hgx, lgx);
        split2(gy, hgy, lgy);
        split2(gz, hgz, lgz);
        const float S = fmaf(gx, gx, fmaf(gy, gy, gz * gz));
        split2(S, hS, lS);
        bf16x8 h0 = (bf16x8){hgx, lgx, hgx, hgy, lgy, hgy, hgz, lgz}; // k0-7
        bf16x8 h1 = (bf16x8){hgz, hS, lS, ONE, ONE, 0, 0, 0};         // k8-15
        // layout: [tile = g>>5][kh][col = g&31], 16B per frag
        short* d = dst + ((size_t)(g >> 5) * 64 + (g & 31)) * 8;
        *(bf16x8*)d = h0;
        *(bf16x8*)(d + 32 * 8) = h1;
    }
}

// ---------- row-min MFMA sweep: block owns 128 rows, sweeps all M cols ----------
// dir0: queries=xyz1, targets=pB2 -> min1 ; dir1: queries=xyz2, targets=pB1 -> min2.
// Direct store, no atomics anywhere.
__global__ __launch_bounds__(THREADS) void cd_mfma(
        const float* __restrict__ xyz1, const float* __restrict__ xyz2,
        const short* __restrict__ pB1, const short* __restrict__ pB2,
        unsigned* __restrict__ mins) {
    __shared__ short sB[TC * 32 / 2];    // 16 tiles x 1KB = 16KB

    const int dir  = blockIdx.z;
    const int b    = blockIdx.y;
    const int tid  = threadIdx.x;
    const int lane = tid & 63;
    const int wave = tid >> 6;

    const float* Q  = (dir ? xyz2 : xyz1) + (size_t)b * N_ * 3;
    const short* pB = (dir ? pB1 : pB2) + (size_t)b * (M_ / 32) * 512;
    unsigned* out   = mins + (dir ? (size_t)B_ * N_ : 0) + (size_t)b * N_
                           + blockIdx.x * QB + wave * 32;

    // ---- A fragment: row = lane&31, k-half = lane>>5 ----
    const int qrow = blockIdx.x * QB + wave * 32 + (lane & 31);
    const float qx = Q[qrow * 3 + 0], qy = Q[qrow * 3 + 1], qz = Q[qrow * 3 + 2];
    short hax, lax, hay, lay, haz, laz, hP, lP;
    split2(-2.0f * qx, hax, lax);
    split2(-2.0f * qy, hay, lay);
    split2(-2.0f * qz, haz, laz);
    const float Pq = fmaf(qx, qx, fmaf(qy, qy, qz * qz));
    split2(Pq, hP, lP);
    const short ONE = (short)0x3F80;
    bf16x8 afrag;
    if (lane < 32) afrag = (bf16x8){hax, hax, lax, hay, hay, lay, haz, haz}; // k0-7
    else           afrag = (bf16x8){laz, ONE, ONE, hP, lP, 0, 0, 0};         // k8-15

    float rmin[16];
#pragma unroll
    for (int r = 0; r < 16; ++r) rmin[r] = INFINITY;

    const f32x16 zacc = {};

    for (int c0 = 0; c0 < M_; c0 += TC) {
        __syncthreads();
        // stage 16KB of precomputed fragments (linear copy)
        {
            const bf16x8* src = (const bf16x8*)(pB + (size_t)(c0 >> 5) * 512);
            bf16x8* dst = (bf16x8*)sB;
#pragma unroll
            for (int p = 0; p < 4; ++p) dst[tid + p * 256] = src[tid + p * 256];
        }
        __syncthreads();

        // 16 tiles; ILP-2, merge pairs with min3
#pragma unroll 2
        for (int tl = 0; tl < TC / 32; tl += 2) {
            bf16x8 b0 = ((bf16x8*)sB)[(tl + 0) * 64 + lane];
            bf16x8 b1 = ((bf16x8*)sB)[(tl + 1) * 64 + lane];
            f32x16 a0 = __builtin_amdgcn_mfma_f32_32x32x16_bf16(afrag, b0, zacc, 0, 0, 0);
            f32x16 a1 = __builtin_amdgcn_mfma_f32_32x32x16_bf16(afrag, b1, zacc, 0, 0, 0);
#pragma unroll
            for (int r = 0; r < 16; ++r)
                rmin[r] = fminf(fminf(rmin[r], a0[r]), a1[r]);   // -> v_min3_f32
        }
    }

    // ---- reduce over the 32 col-lanes (k-half groups hold disjoint rows) ----
#pragma unroll
    for (int s = 1; s <= 16; s <<= 1) {
#pragma unroll
        for (int r = 0; r < 16; ++r) rmin[r] = fminf(rmin[r], __shfl_xor(rmin[r], s));
    }
    if ((lane & 31) == 0) {
        const int h = lane >> 5;
#pragma unroll
        for (int r = 0; r < 16; ++r) {
            const int row = (r & 3) + 8 * (r >> 2) + 4 * h;   // verified C/D mapping
            out[row] = __float_as_uint(fmaxf(rmin[r], 0.0f));
        }
    }
}

// ---------- reduce A: 256 blocks x 256 -> partials (sqrt of d^2) ----------
__global__ __launch_bounds__(RBLK) void cd_reduceA(
        const unsigned* __restrict__ mins, float* __restrict__ partials) {
    __shared__ float sdata[RBLK];
    const int tid = threadIdx.x;
    const int i = blockIdx.x * RBLK + tid;
    float v = sqrtf(__uint_as_float(mins[i]));
    float scale = (i < B_ * N_) ? (1.0f / (float)(B_ * N_)) : (1.0f / (float)(B_ * M_));
    sdata[tid] = v * scale;
    __syncthreads();
    for (int off = RBLK / 2; off > 0; off >>= 1) {
        if (tid < off) sdata[tid] += sdata[tid + off];
        __syncthreads();
    }
    if (tid == 0) partials[blockIdx.x] = sdata[0];
}

__global__ __launch_bounds__(RBLK) void cd_reduceB(
        const float* __restrict__ partials, float* __restrict__ out) {
    __shared__ float sdata[RBLK];
    const int tid = threadIdx.x;
    sdata[tid] = partials[tid];
    __syncthreads();
    for (int off = RBLK / 2; off > 0; off >>= 1) {
        if (tid < off) sdata[tid] += sdata[tid + off];
        __syncthreads();
    }
    if (tid == 0) out[0] = sdata[0];
}

// ---------- fallback (tiny ws): scalar full-loop + atomicAdd ----------
#define FQPT 8
#define FTCH 256
__global__ void cd_zero_out(float* out) { if (threadIdx.x == 0) out[0] = 0.0f; }

__global__ __launch_bounds__(THREADS) void cd_full_kernel(
        const float* __restrict__ Q, const float* __restrict__ T,
        float* __restrict__ out, int nq, int nt, float scale) {
    __shared__ float4 tile[FTCH];
    __shared__ float sdata[THREADS];
    const int b = blockIdx.y;
    const float* Qb = Q + (size_t)b * nq * 3;
    const float* Tbase = T + (size_t)b * nt * 3;
    float m2x[FQPT], m2y[FQPT], m2z[FQPT], c[FQPT], dmin[FQPT];
    const int qbase = blockIdx.x * (THREADS * FQPT) + threadIdx.x;
#pragma unroll
    for (int k = 0; k < FQPT; ++k) {
        int q = qbase + k * THREADS;
        float x = Qb[q * 3 + 0], y = Qb[q * 3 + 1], z = Qb[q * 3 + 2];
        m2x[k] = -2.0f * x; m2y[k] = -2.0f * y; m2z[k] = -2.0f * z;
        c[k] = x * x + y * y + z * z;
        dmin[k] = INFINITY;
    }
    for (int t0 = 0; t0 < nt; t0 += FTCH) {
        __syncthreads();
        for (int j = threadIdx.x; j < FTCH; j += THREADS) {
            const float* Tb = Tbase + (size_t)(t0 + j) * 3;
            float x = Tb[0], y = Tb[1], z = Tb[2];
            tile[j] = make_float4(x, y, z, x * x + y * y + z * z);
        }
        __syncthreads();
#pragma unroll 4
        for (int j = 0; j < FTCH; ++j) {
            float4 t = tile[j];
#pragma unroll
            for (int k = 0; k < FQPT; ++k) {
                float d = fmaf(m2x[k], t.x, t.w);
                d = fmaf(m2y[k], t.y, d);
                d = fmaf(m2z[k], t.z, d);
                dmin[k] = fminf(dmin[k], d);
            }
        }
    }
    float s = 0.0f;
#pragma unroll
    for (int k = 0; k < FQPT; ++k) s += sqrtf(fmaxf(c[k] + dmin[k], 0.0f));
    sdata[threadIdx.x] = s;
    __syncthreads();
    for (int off = THREADS / 2; off > 0; off >>= 1) {
        if (threadIdx.x < off) sdata[threadIdx.x] += sdata[threadIdx.x + off];
        __syncthreads();
    }
    if (threadIdx.x == 0) atomicAdd(out, sdata[0] * scale);
}

extern "C" void kernel_launch(void* const* d_in, const int* in_sizes, int n_in,
                              void* d_out, int out_size, void* d_ws, size_t ws_size,
                              hipStream_t stream) {
    const float* xyz1 = (const float*)d_in[0];
    const float* xyz2 = (const float*)d_in[1];
    float* out = (float*)d_out;

    if (ws_size >= WS_NEED) {
        unsigned* mins = (unsigned*)d_ws;
        float* partials = (float*)((char*)d_ws + (size_t)NQTOT * 4);
        short* pB1 = (short*)((char*)d_ws + PB1_OFF);
        short* pB2 = (short*)((char*)d_ws + PB2_OFF);

        cd_pack<<<B_ * M_ / 256, 256, 0, stream>>>(xyz1, xyz2, pB1, pB2);

        dim3 g(N_ / QB, B_, 2);   // (64, 4, 2) = 512 blocks
        cd_mfma<<<g, THREADS, 0, stream>>>(xyz1, xyz2, pB1, pB2, mins);

        cd_reduceA<<<NQTOT / RBLK, RBLK, 0, stream>>>(mins, partials);
        cd_reduceB<<<1, RBLK, 0, stream>>>(partials, out);
    } else {
        cd_zero_out<<<1, 64, 0, stream>>>(out);
        dim3 g1(N_ / (THREADS * FQPT), B_);
        cd_full_kernel<<<g1, THREADS, 0, stream>>>(xyz1, xyz2, out, N_, M_,
                                                   1.0f / (float)(B_ * N_));
        dim3 g2(M_ / (THREADS * FQPT), B_);
        cd_full_kernel<<<g2, THREADS, 0, stream>>>(xyz2, xyz1, out, M_, N_,
                                                   1.0f / (float)(B_ * M_));
    }
}

// Round 14
// 34.663 us; speedup vs baseline: 1.7641x; 1.3511x over previous
//
#include <hip/hip_runtime.h>
#include <math.h>

#define B_ 4
#define N_ 8192
#define M_ 8192
#define THREADS 512     // 8 waves per block
#define QB 256          // query rows per block (8 waves x 32)
#define MSPLIT 2
#define MCH (M_ / MSPLIT)    // 4096 cols per block
#define TC 512               // targets per LDS chunk (16 tiles, 16KB)
#define NCH (MCH / TC)       // 8 chunks
#define NQTOT (B_ * (N_ + M_))
#define RBLK 256
#define PB_BYTES ((size_t)B_ * M_ * 32)
#define PART_OFF ((size_t)2 * NQTOT * 4)
#define PB1_OFF (PART_OFF + RBLK * 4)
#define PB2_OFF (PB1_OFF + PB_BYTES)
#define WS_NEED (PB2_OFF + PB_BYTES)

typedef __attribute__((ext_vector_type(8)))  short bf16x8;
typedef __attribute__((ext_vector_type(16))) float f32x16;

__device__ __forceinline__ unsigned short rne_bf16(float f) {
    unsigned u = __float_as_uint(f);
    return (unsigned short)((u + 0x7FFFu + ((u >> 16) & 1u)) >> 16);
}
__device__ __forceinline__ float bf16_up(unsigned short h) {
    return __uint_as_float(((unsigned)h) << 16);
}
__device__ __forceinline__ void split2(float v, short& hi, short& lo) {
    unsigned short h = rne_bf16(v);
    hi = (short)h;
    lo = (short)rne_bf16(v - bf16_up(h));
}
__device__ __forceinline__ void gl_lds16(const void* g, void* l) {
    __builtin_amdgcn_global_load_lds(
        (const __attribute__((address_space(1))) void*)g,
        (__attribute__((address_space(3))) void*)l, 16, 0, 0);
}

// ---------- pack both clouds into MFMA B-fragments ----------
__global__ __launch_bounds__(256) void cd_pack(
        const float* __restrict__ xyz1, const float* __restrict__ xyz2,
        short* __restrict__ pB1, short* __restrict__ pB2) {
    const int g = blockIdx.x * 256 + threadIdx.x;
    const short ONE = (short)0x3F80;
#pragma unroll
    for (int s = 0; s < 2; ++s) {
        const float* src = s ? xyz2 : xyz1;
        short* dst = s ? pB2 : pB1;
        const float gx = src[g * 3 + 0], gy = src[g * 3 + 1], gz = src[g * 3 + 2];
        short hgx, lgx, hgy, lgy, hgz, lgz, hS, lS;
        split2(gx, hgx, lgx);
        split2(gy, hgy, lgy);
        split2(gz, hgz, lgz);
        const float S = fmaf(gx, gx, fmaf(gy, gy, gz * gz));
        split2(S, hS, lS);
        bf16x8 h0 = (bf16x8){hgx, lgx, hgx, hgy, lgy, hgy, hgz, lgz}; // k0-7
        bf16x8 h1 = (bf16x8){hgz, hS, lS, ONE, ONE, 0, 0, 0};         // k8-15
        short* d = dst + ((size_t)(g >> 5) * 64 + (g & 31)) * 8;      // [tile][kh][col]
        *(bf16x8*)d = h0;
        *(bf16x8*)(d + 32 * 8) = h1;
    }
}

// ---------- row-min MFMA sweep: 8 waves, dbuf global_load_lds, no atomics ----------
// z: dir = z>>1, half = z&1. Each (dir,half) writes a disjoint output slab.
__global__ __launch_bounds__(THREADS) void cd_mfma(
        const float* __restrict__ xyz1, const float* __restrict__ xyz2,
        const short* __restrict__ pB1, const short* __restrict__ pB2,
        unsigned* __restrict__ mins) {
    __shared__ short sB[2 * TC * 16];    // 2 x 16KB

    const int dir  = blockIdx.z >> 1;
    const int half = blockIdx.z & 1;
    const int b    = blockIdx.y;
    const int tid  = threadIdx.x;
    const int lane = tid & 63;
    const int wave = tid >> 6;

    const float* Q = (dir ? xyz2 : xyz1) + (size_t)b * N_ * 3;
    const char* gT = (const char*)(dir ? pB1 : pB2)
                     + (size_t)b * (M_ / 32) * 1024 + (size_t)half * (MCH / 32) * 1024;
    unsigned* out  = mins + (size_t)half * NQTOT + (dir ? (size_t)B_ * N_ : 0)
                     + (size_t)b * N_ + blockIdx.x * QB + wave * 32;

    // ---- A fragment ----
    const int qrow = blockIdx.x * QB + wave * 32 + (lane & 31);
    const float qx = Q[qrow * 3 + 0], qy = Q[qrow * 3 + 1], qz = Q[qrow * 3 + 2];
    short hax, lax, hay, lay, haz, laz, hP, lP;
    split2(-2.0f * qx, hax, lax);
    split2(-2.0f * qy, hay, lay);
    split2(-2.0f * qz, haz, laz);
    const float Pq = fmaf(qx, qx, fmaf(qy, qy, qz * qz));
    split2(Pq, hP, lP);
    const short ONE = (short)0x3F80;
    bf16x8 afrag;
    if (lane < 32) afrag = (bf16x8){hax, hax, lax, hay, hay, lay, haz, haz};
    else           afrag = (bf16x8){laz, ONE, ONE, hP, lP, 0, 0, 0};

    float rmin[16];
#pragma unroll
    for (int r = 0; r < 16; ++r) rmin[r] = INFINITY;
    const f32x16 zacc = {};

    // stage chunk c into buffer buf: 8 waves x 2 calls x 1KB = 16KB, linear
    auto STAGE = [&](int buf, int c) {
        const char* g = gT + (size_t)c * 16384 + wave * 1024 + lane * 16;
        char* l = (char*)sB + buf * 16384 + wave * 1024;
        gl_lds16(g, l);
        gl_lds16(g + 8192, l + 8192);
    };

    int cur = 0;
    STAGE(0, 0);
    __syncthreads();                       // drain vmcnt: buf0 ready

    for (int c = 0; c < NCH; ++c) {
        if (c + 1 < NCH) STAGE(cur ^ 1, c + 1);   // prefetch under compute
        const bf16x8* bb = (const bf16x8*)sB + cur * 1024;
#pragma unroll 2
        for (int tl = 0; tl < TC / 32; tl += 2) {
            bf16x8 b0 = bb[(tl + 0) * 64 + lane];
            bf16x8 b1 = bb[(tl + 1) * 64 + lane];
            f32x16 a0 = __builtin_amdgcn_mfma_f32_32x32x16_bf16(afrag, b0, zacc, 0, 0, 0);
            f32x16 a1 = __builtin_amdgcn_mfma_f32_32x32x16_bf16(afrag, b1, zacc, 0, 0, 0);
#pragma unroll
            for (int r = 0; r < 16; ++r)
                rmin[r] = fminf(fminf(rmin[r], a0[r]), a1[r]);   // v_min3_f32
        }
        __syncthreads();                   // readers done + prefetch drained
        cur ^= 1;
    }

    // ---- reduce across 32 col-lanes, direct store ----
#pragma unroll
    for (int s = 1; s <= 16; s <<= 1) {
#pragma unroll
        for (int r = 0; r < 16; ++r) rmin[r] = fminf(rmin[r], __shfl_xor(rmin[r], s));
    }
    if ((lane & 31) == 0) {
        const int h = lane >> 5;
#pragma unroll
        for (int r = 0; r < 16; ++r) {
            const int row = (r & 3) + 8 * (r >> 2) + 4 * h;   // verified C/D mapping
            out[row] = __float_as_uint(fmaxf(rmin[r], 0.0f));
        }
    }
}

// ---------- reduce A: merge the two halves, sqrt, partial sums ----------
__global__ __launch_bounds__(RBLK) void cd_reduceA(
        const unsigned* __restrict__ mins, float* __restrict__ partials) {
    __shared__ float sdata[RBLK];
    const int tid = threadIdx.x;
    const int i = blockIdx.x * RBLK + tid;
    float fa = __uint_as_float(mins[i]);
    float fb = __uint_as_float(mins[(size_t)NQTOT + i]);
    float v = sqrtf(fminf(fa, fb));
    float scale = (i < B_ * N_) ? (1.0f / (float)(B_ * N_)) : (1.0f / (float)(B_ * M_));
    sdata[tid] = v * scale;
    __syncthreads();
    for (int off = RBLK / 2; off > 0; off >>= 1) {
        if (tid < off) sdata[tid] += sdata[tid + off];
        __syncthreads();
    }
    if (tid == 0) partials[blockIdx.x] = sdata[0];
}

__global__ __launch_bounds__(RBLK) void cd_reduceB(
        const float* __restrict__ partials, float* __restrict__ out) {
    __shared__ float sdata[RBLK];
    const int tid = threadIdx.x;
    sdata[tid] = partials[tid];
    __syncthreads();
    for (int off = RBLK / 2; off > 0; off >>= 1) {
        if (tid < off) sdata[tid] += sdata[tid + off];
        __syncthreads();
    }
    if (tid == 0) out[0] = sdata[0];
}

// ---------- fallback (tiny ws) ----------
#define FQPT 8
#define FTCH 256
__global__ void cd_zero_out(float* out) { if (threadIdx.x == 0) out[0] = 0.0f; }

__global__ __launch_bounds__(256) void cd_full_kernel(
        const float* __restrict__ Q, const float* __restrict__ T,
        float* __restrict__ out, int nq, int nt, float scale) {
    __shared__ float4 tile[FTCH];
    __shared__ float sdata[256];
    const int b = blockIdx.y;
    const float* Qb = Q + (size_t)b * nq * 3;
    const float* Tbase = T + (size_t)b * nt * 3;
    float m2x[FQPT], m2y[FQPT], m2z[FQPT], c[FQPT], dmin[FQPT];
    const int qbase = blockIdx.x * (256 * FQPT) + threadIdx.x;
#pragma unroll
    for (int k = 0; k < FQPT; ++k) {
        int q = qbase + k * 256;
        float x = Qb[q * 3 + 0], y = Qb[q * 3 + 1], z = Qb[q * 3 + 2];
        m2x[k] = -2.0f * x; m2y[k] = -2.0f * y; m2z[k] = -2.0f * z;
        c[k] = x * x + y * y + z * z;
        dmin[k] = INFINITY;
    }
    for (int t0 = 0; t0 < nt; t0 += FTCH) {
        __syncthreads();
        for (int j = threadIdx.x; j < FTCH; j += 256) {
            const float* Tb = Tbase + (size_t)(t0 + j) * 3;
            float x = Tb[0], y = Tb[1], z = Tb[2];
            tile[j] = make_float4(x, y, z, x * x + y * y + z * z);
        }
        __syncthreads();
#pragma unroll 4
        for (int j = 0; j < FTCH; ++j) {
            float4 t = tile[j];
#pragma unroll
            for (int k = 0; k < FQPT; ++k) {
                float d = fmaf(m2x[k], t.x, t.w);
                d = fmaf(m2y[k], t.y, d);
                d = fmaf(m2z[k], t.z, d);
                dmin[k] = fminf(dmin[k], d);
            }
        }
    }
    float s = 0.0f;
#pragma unroll
    for (int k = 0; k < FQPT; ++k) s += sqrtf(fmaxf(c[k] + dmin[k], 0.0f));
    sdata[threadIdx.x] = s;
    __syncthreads();
    for (int off = 128; off > 0; off >>= 1) {
        if (threadIdx.x < off) sdata[threadIdx.x] += sdata[threadIdx.x + off];
        __syncthreads();
    }
    if (threadIdx.x == 0) atomicAdd(out, sdata[0] * scale);
}

extern "C" void kernel_launch(void* const* d_in, const int* in_sizes, int n_in,
                              void* d_out, int out_size, void* d_ws, size_t ws_size,
                              hipStream_t stream) {
    const float* xyz1 = (const float*)d_in[0];
    const float* xyz2 = (const float*)d_in[1];
    float* out = (float*)d_out;

    if (ws_size >= WS_NEED) {
        unsigned* mins = (unsigned*)d_ws;
        float* partials = (float*)((char*)d_ws + PART_OFF);
        short* pB1 = (short*)((char*)d_ws + PB1_OFF);
        short* pB2 = (short*)((char*)d_ws + PB2_OFF);

        cd_pack<<<B_ * M_ / 256, 256, 0, stream>>>(xyz1, xyz2, pB1, pB2);

        dim3 g(N_ / QB, B_, 4);   // (32, 4, dir*2+half) = 512 blocks x 8 waves
        cd_mfma<<<g, THREADS, 0, stream>>>(xyz1, xyz2, pB1, pB2, mins);

        cd_reduceA<<<NQTOT / RBLK, RBLK, 0, stream>>>(mins, partials);
        cd_reduceB<<<1, RBLK, 0, stream>>>(partials, out);
    } else {
        cd_zero_out<<<1, 64, 0, stream>>>(out);
        dim3 g1(N_ / (256 * FQPT), B_);
        cd_full_kernel<<<g1, 256, 0, stream>>>(xyz1, xyz2, out, N_, M_,
                                               1.0f / (float)(B_ * N_));
        dim3 g2(M_ / (256 * FQPT), B_);
        cd_full_kernel<<<g2, 256, 0, stream>>>(xyz2, xyz1, out, M_, N_,
                                               1.0f / (float)(B_ * M_));
    }
}